// Round 3
// baseline (281.561 us; speedup 1.0000x reference)
//
#include <hip/hip_runtime.h>
#include <math.h>

#define BINS 30

static constexpr int BLOCK = 256;
static constexpr int GRID  = 1024;  // 4 resident blocks/CU (33 KiB LDS) x 256 CUs
static constexpr int SLOTS = 32;    // 30 bins + slot 30 = trash (out-of-range), 31 pad

__device__ __forceinline__ float wave_sum(float v) {
    #pragma unroll
    for (int o = 32; o > 0; o >>= 1) v += __shfl_xor(v, o, 64);
    return v;
}

// Per-thread private packed histograms: h[slot*256 + tid] holds
// x-count in bits 0..15 (+1) and y-count in bits 16..31 (+65536).
// Increment via atomicAdd -> ds_add_u32, fire-and-forget: NO waitcnt, no
// dependent read-modify-write chain (the R1 latency bottleneck).
// Bank = tid%32: conflict-free; per-thread private: no same-address serialization.
// Max x count/thread/slot = 128 elements; column sum <= 32768 < 2^16 -> packed
// u32 sums are exact with no field carry.
__global__ __launch_bounds__(BLOCK, 4) void hist_kernel(
        const float* __restrict__ x, const float* __restrict__ y,
        int n4, unsigned int* __restrict__ g_hist)
{
    __shared__ unsigned int h[SLOTS * BLOCK];     // 32 KiB
    __shared__ unsigned int partial[BLOCK];       // +1 KiB
    const int tid = threadIdx.x;

    #pragma unroll
    for (int i = 0; i < SLOTS; ++i) h[i * BLOCK + tid] = 0u;
    __syncthreads();

    const float4* __restrict__ x4 = (const float4*)x;
    const float4* __restrict__ y4 = (const float4*)y;

    const int stride = gridDim.x * BLOCK;
    for (int i = blockIdx.x * BLOCK + tid; i < n4; i += stride) {
        float4 a = x4[i];
        float4 b = y4[i];
        // torch.histc: idx = floor((v+4)*3.75) clipped to [0,29]; |v|>4 -> trash slot 30
        #define PROC(v, inc) {                                              \
            float q = ((v) + 4.0f) * 3.75f;   /* >= 0 whenever valid */     \
            int idx = (int)q;                                               \
            idx = idx > 29 ? 29 : idx;        /* v == 4.0 -> last bin */    \
            bool valid = fabsf(v) <= 4.0f;    /* abs modifier is free */    \
            int slot = valid ? idx : 30;                                    \
            atomicAdd(&h[slot * BLOCK + tid], (inc));  /* ds_add_u32 */     \
        }
        PROC(a.x, 1u)      PROC(a.y, 1u)      PROC(a.z, 1u)      PROC(a.w, 1u)
        PROC(b.x, 65536u)  PROC(b.y, 65536u)  PROC(b.z, 65536u)  PROC(b.w, 65536u)
        #undef PROC
    }
    __syncthreads();

    // Reduce 256 columns per slot (packed u32 sums are exact, see above).
    // Thread t: slot t&31, 32-column chunk (t>>5), column rotated by t.
    const int slot = tid & 31;
    const int c0   = (tid >> 5) * 32;
    unsigned int s = 0;
    #pragma unroll 8
    for (int c = 0; c < 32; ++c) {
        int col = c0 + ((c + tid) & 31);
        s += h[slot * BLOCK + col];
    }
    partial[tid] = s;
    __syncthreads();
    if (tid < 32) {
        unsigned int tot = 0;
        #pragma unroll
        for (int g = 0; g < 8; ++g) tot += partial[g * 32 + tid];
        if (tid < BINS) {
            atomicAdd(&g_hist[tid],      tot & 0xFFFFu);  // x histogram
            atomicAdd(&g_hist[32 + tid], tot >> 16);      // y histogram
        }
    }
}

__global__ void finalize_kernel(const unsigned int* __restrict__ g_hist,
                                float* __restrict__ out)
{
    const int t = threadIdx.x;
    const bool active = t < BINS;
    float hx = active ? (float)g_hist[t]      : 0.0f;
    float hy = active ? (float)g_hist[32 + t] : 0.0f;
    float hj = hx + hy;                      // joint = hist_x + hist_y exactly

    float Sx = wave_sum(hx);
    float Sy = wave_sum(hy);
    float Sj = wave_sum(hj);

    float px = hx / Sx;
    float py = hy / Sy;
    float jp = hj / Sj;

    // mi = 30 * sum_j jp_j*(log jp_j - log py_j) - (sum_j jp_j) * (sum_i log px_i)
    float term = active ? jp * (logf(jp) - logf(py)) : 0.0f;
    float lpx  = active ? logf(px) : 0.0f;
    float sjp  = wave_sum(active ? jp : 0.0f);

    float st = wave_sum(term);
    float sl = wave_sum(lpx);
    if (t == 0) out[0] = -((float)BINS * st - sjp * sl);
}

extern "C" void kernel_launch(void* const* d_in, const int* in_sizes, int n_in,
                              void* d_out, int out_size, void* d_ws, size_t ws_size,
                              hipStream_t stream) {
    const float* x = (const float*)d_in[0];
    const float* y = (const float*)d_in[1];
    const int n = in_sizes[0];               // 2^25, divisible by 4
    unsigned int* g_hist = (unsigned int*)d_ws;

    hipMemsetAsync(d_ws, 0, 64 * sizeof(unsigned int), stream);  // ws is poisoned 0xAA
    hist_kernel<<<GRID, BLOCK, 0, stream>>>(x, y, n >> 2, g_hist);
    finalize_kernel<<<1, 64, 0, stream>>>(g_hist, (float*)d_out);
}

// Round 5
// 258.526 us; speedup vs baseline: 1.0891x; 1.0891x over previous
//
#include <hip/hip_runtime.h>
#include <math.h>

#define BINS 30

static constexpr int BLOCK  = 256;
static constexpr int GRID   = 1024;  // 4 resident blocks/CU (33 KiB LDS) x 256 CUs
static constexpr int SLOTS  = 32;    // 30 bins + slot 30 = trash (out-of-range), 31 pad
static constexpr int UNROLL = 4;     // float4 loads per array per superiteration

typedef float f32x4 __attribute__((ext_vector_type(4)));  // native vec: OK for nontemporal builtins

__device__ __forceinline__ float wave_sum(float v) {
    #pragma unroll
    for (int o = 32; o > 0; o >>= 1) v += __shfl_xor(v, o, 64);
    return v;
}

// Per-thread private packed histograms in LDS: h[slot*256 + tid] holds
// x-count in bits 0..15 (+1), y-count in bits 16..31 (+65536).
// ds_add_u32 fire-and-forget (no waitcnt, no RMW chain); bank = tid%32
// (conflict-free, zero same-address contention). Max x-count/thread/slot
// = 128 -> column sums < 2^16, packed u32 sums exact.
//
// R4 = R3 with the compile fix: the hot loop issues 8 INDEPENDENT coalesced
// dwordx4 loads back-to-back (8 KiB/wave in flight vs 2 KiB in R2) before
// consuming, breaking the per-iteration full vmcnt(0) drain that capped
// effective read BW at ~2.5 TB/s across R0-R2.
__global__ __launch_bounds__(BLOCK, 4) void hist_kernel(
        const float* __restrict__ x, const float* __restrict__ y,
        int n4, unsigned int* __restrict__ g_hist)
{
    __shared__ unsigned int h[SLOTS * BLOCK];     // 32 KiB
    __shared__ unsigned int partial[BLOCK];       // +1 KiB
    const int tid = threadIdx.x;

    #pragma unroll
    for (int i = 0; i < SLOTS; ++i) h[i * BLOCK + tid] = 0u;
    __syncthreads();

    const f32x4* __restrict__ x4 = (const f32x4*)x;
    const f32x4* __restrict__ y4 = (const f32x4*)y;

    // torch.histc: idx = floor((v+4)*3.75) clipped to [0,29]; |v|>4 -> trash slot 30
    #define PROC(v, inc) {                                              \
        float q = ((v) + 4.0f) * 3.75f;                                 \
        int idx = (int)q;                                               \
        idx = idx > 29 ? 29 : idx;        /* v == 4.0 -> last bin */    \
        bool valid = fabsf(v) <= 4.0f;                                  \
        int slot = valid ? idx : 30;                                    \
        atomicAdd(&h[slot * BLOCK + tid], (inc));  /* ds_add_u32 */     \
    }
    #define PROC4(f, inc) { PROC((f).x, inc) PROC((f).y, inc) PROC((f).z, inc) PROC((f).w, inc) }

    const int span   = GRID * BLOCK * UNROLL;      // float4 per superiteration
    const int chunk0 = blockIdx.x * (BLOCK * UNROLL);

    for (int chunk = chunk0; chunk + BLOCK * UNROLL <= n4; chunk += span) {
        f32x4 a[UNROLL], b[UNROLL];
        #pragma unroll
        for (int j = 0; j < UNROLL; ++j)
            a[j] = __builtin_nontemporal_load(&x4[chunk + j * BLOCK + tid]);
        #pragma unroll
        for (int j = 0; j < UNROLL; ++j)
            b[j] = __builtin_nontemporal_load(&y4[chunk + j * BLOCK + tid]);
        #pragma unroll
        for (int j = 0; j < UNROLL; ++j) {
            PROC4(a[j], 1u)
            PROC4(b[j], 65536u)
        }
    }

    // Tail (empty for the benchmark's 2^23 float4s; kept for generality)
    const int tail_start = n4 - (n4 % span);
    for (int i = tail_start + blockIdx.x * BLOCK + tid; i < n4; i += GRID * BLOCK) {
        f32x4 a = x4[i], b = y4[i];
        PROC4(a, 1u)
        PROC4(b, 65536u)
    }
    #undef PROC4
    #undef PROC
    __syncthreads();

    // Reduce 256 columns per slot (packed u32 sums exact).
    const int slot = tid & 31;
    const int c0   = (tid >> 5) * 32;
    unsigned int s = 0;
    #pragma unroll 8
    for (int c = 0; c < 32; ++c) {
        int col = c0 + ((c + tid) & 31);
        s += h[slot * BLOCK + col];
    }
    partial[tid] = s;
    __syncthreads();
    if (tid < 32) {
        unsigned int tot = 0;
        #pragma unroll
        for (int g = 0; g < 8; ++g) tot += partial[g * 32 + tid];
        if (tid < BINS) {
            atomicAdd(&g_hist[tid],      tot & 0xFFFFu);  // x histogram
            atomicAdd(&g_hist[32 + tid], tot >> 16);      // y histogram
        }
    }
}

__global__ void finalize_kernel(const unsigned int* __restrict__ g_hist,
                                float* __restrict__ out)
{
    const int t = threadIdx.x;
    const bool active = t < BINS;
    float hx = active ? (float)g_hist[t]      : 0.0f;
    float hy = active ? (float)g_hist[32 + t] : 0.0f;
    float hj = hx + hy;                      // joint = hist_x + hist_y exactly

    float Sx = wave_sum(hx);
    float Sy = wave_sum(hy);
    float Sj = wave_sum(hj);

    float px = hx / Sx;
    float py = hy / Sy;
    float jp = hj / Sj;

    // mi = 30 * sum_j jp_j*(log jp_j - log py_j) - (sum_j jp_j) * (sum_i log px_i)
    float term = active ? jp * (logf(jp) - logf(py)) : 0.0f;
    float lpx  = active ? logf(px) : 0.0f;
    float sjp  = wave_sum(active ? jp : 0.0f);

    float st = wave_sum(term);
    float sl = wave_sum(lpx);
    if (t == 0) out[0] = -((float)BINS * st - sjp * sl);
}

extern "C" void kernel_launch(void* const* d_in, const int* in_sizes, int n_in,
                              void* d_out, int out_size, void* d_ws, size_t ws_size,
                              hipStream_t stream) {
    const float* x = (const float*)d_in[0];
    const float* y = (const float*)d_in[1];
    const int n = in_sizes[0];               // 2^25, divisible by 4
    unsigned int* g_hist = (unsigned int*)d_ws;

    (void)hipMemsetAsync(d_ws, 0, 64 * sizeof(unsigned int), stream);  // ws is poisoned 0xAA
    hist_kernel<<<GRID, BLOCK, 0, stream>>>(x, y, n >> 2, g_hist);
    finalize_kernel<<<1, 64, 0, stream>>>(g_hist, (float*)d_out);
}